// Round 11
// baseline (76.665 us; speedup 1.0000x reference)
//
#include <hip/hip_runtime.h>

// d_ws layout:
//  uint2 wt[3408]: lo = half2(cos, sin) [X-dot], hi = half2(-sin, cos) [Y-dot]
//   [0..15]     conv1 (o*4 + dy*2 + dx)
//   [16..527]   conv2 (o*64 + c*16 + dy*4 + dx)   (legacy, unused by main)
//   [528..3407] ff    (f*10 + n)
//  byte 27264: uint4 Btab[256] — MFMA B-fragments for stage 2:
//   entry e=(c*4+dy)*16+n holds 8 f16 (j -> dx=j>>1, comp=j&1);
//   col n: even -> X column (cos,sin), odd -> Y column (-sin,cos), o=n>>1.
#define WT_W1 0
#define WT_FF 528
#define WT_B2_BYTES (3408 * 8)

typedef _Float16 h2  __attribute__((ext_vector_type(2)));
typedef _Float16 v8h __attribute__((ext_vector_type(8)));
typedef float    f4  __attribute__((ext_vector_type(4)));

__device__ __forceinline__ float fdot2(unsigned a, unsigned b, float c) {
    return __builtin_amdgcn_fdot2(__builtin_bit_cast(h2, a),
                                  __builtin_bit_cast(h2, b), c, false);
}
__device__ __forceinline__ unsigned packh2(float x, float y) {
    h2 h; h.x = (_Float16)x; h.y = (_Float16)y;
    return __builtin_bit_cast(unsigned, h);
}

__global__ void ringnn_setup(const float* __restrict__ w1,
                             const float* __restrict__ w2,
                             const float* __restrict__ ffw,
                             uint2* __restrict__ wt) {
    int t = blockIdx.x * blockDim.x + threadIdx.x;
    if (t < 3408) {
        float a;
        if (t < 16)        a = w1[t];
        else if (t < 528)  a = w2[t - 16];
        else               a = ffw[t - 528];
        float s, c;
        __sincosf(a, &s, &c);
        uint2 v;
        v.x = packh2(c, s);
        v.y = packh2(-s, c);
        wt[t] = v;
    } else if (t < 3408 + 256) {
        // MFMA B-fragment table for stage 2.
        const int e  = t - 3408;
        const int nn = e & 15;
        const int dy = (e >> 4) & 3;
        const int c  = e >> 6;
        const int o  = nn >> 1;
        unsigned d[4];
        #pragma unroll
        for (int dx = 0; dx < 4; ++dx) {
            float a = w2[o * 64 + c * 16 + dy * 4 + dx];
            float s, cc;
            __sincosf(a, &s, &cc);
            d[dx] = (nn & 1) ? packh2(-s, cc) : packh2(cc, s);
        }
        uint4* Bt = (uint4*)((char*)wt + WT_B2_BYTES);
        Bt[e] = make_uint4(d[0], d[1], d[2], d[3]);
    }
}

// 256 threads = 4 waves; 2 images per block; grid 2048 -> 32 waves/CU.
// Stage 1: 2 waves (128 lanes)/image; ALL global loads hoisted ahead of the
//          sincos chains (one exposed memory latency per wave, not two).
// Stage 2: MFMA 16x16x32 f16, 5 M-tiles over 72 positions, 4 waves.
// Stage 3: 2 waves/image, 5 outputs/wave, 12-lane groups; 2-way split
//          accumulators halve the serial fdot2 chain (24 -> 12).
// NOTE: plain __launch_bounds__ — (256,8) caused catastrophic spill (R3).
__global__ __launch_bounds__(256) void ringnn_main(
    const float* __restrict__ x,
    const uint2* __restrict__ wt,
    float* __restrict__ out)
{
    __shared__ __align__(16) unsigned cs1[2][784];  // [img][c*196+i*14+j], half2
    __shared__ __align__(16) unsigned cs2[2][288];  // [img][(i*6+j)*8+o], half2

    const int t     = threadIdx.x;
    const int wave  = t >> 6;               // 0..3
    const int lane  = t & 63;
    const int img   = t >> 7;               // 0..1 (stages 1,3)
    const int tid   = t & 127;              // lane within the image's 2 waves
    const int b0    = blockIdx.x * 2;
    const float* xb = x + (b0 + img) * 784;

    // ---- Stage 1: sincos from global + 2x2/s2 conv, 1->4 ch ----
    // Exactly 2 candidate positions per lane: tid and tid+128.
    const int  pos1 = tid + 128;
    const bool has1 = (pos1 < 196);
    const int  i0 = tid / 14,  j0 = tid - i0 * 14;
    const int  i1c = pos1 / 14, j1c = pos1 - i1c * 14;
    const float* pxA = xb + (2 * i0) * 28 + 2 * j0;
    const float* pxB = has1 ? (xb + (2 * i1c) * 28 + 2 * j1c) : pxA;
    // Hoist all 4 independent 8B loads: single exposed latency window.
    float2 A0 = *(const float2*)(pxA);
    float2 A1 = *(const float2*)(pxA + 28);
    float2 B0 = *(const float2*)(pxB);
    float2 B1 = *(const float2*)(pxB + 28);

    #pragma unroll
    for (int it = 0; it < 2; ++it) {
        if (it == 1 && !has1) break;
        const int pos = (it == 0) ? tid : pos1;
        float2 p0 = (it == 0) ? A0 : B0;
        float2 p1 = (it == 0) ? A1 : B1;
        float s0, c0, s1, c1, s2, c2, s3, c3;
        __sincosf(p0.x, &s0, &c0);
        __sincosf(p0.y, &s1, &c1);
        __sincosf(p1.x, &s2, &c2);
        __sincosf(p1.y, &s3, &c3);
        unsigned v0 = packh2(c0, s0), v1 = packh2(c1, s1);
        unsigned v2 = packh2(c2, s2), v3 = packh2(c3, s3);
        #pragma unroll
        for (int o = 0; o < 4; ++o) {
            uint2 wa = wt[WT_W1 + o * 4 + 0], wb = wt[WT_W1 + o * 4 + 1];
            uint2 wc = wt[WT_W1 + o * 4 + 2], wd = wt[WT_W1 + o * 4 + 3];
            float X = 0.f, Y = 0.f;
            X = fdot2(v0, wa.x, X); Y = fdot2(v0, wa.y, Y);
            X = fdot2(v1, wb.x, X); Y = fdot2(v1, wb.y, Y);
            X = fdot2(v2, wc.x, X); Y = fdot2(v2, wc.y, Y);
            X = fdot2(v3, wd.x, X); Y = fdot2(v3, wd.y, Y);
            float rinv = rsqrtf(fmaxf(fmaf(X, X, Y * Y), 1e-30f));
            cs1[img][o * 196 + pos] = packh2(X * rinv, Y * rinv);
        }
    }

    // B-fragments: entry (c*4+quad)*16+n -> index c*64 + lane: coalesced.
    const int n    = lane & 15;
    const int quad = lane >> 4;
    const uint4* Bt = (const uint4*)((const char*)wt + WT_B2_BYTES);
    uint4 bf0 = Bt[lane];
    uint4 bf1 = Bt[64 + lane];
    uint4 bf2 = Bt[128 + lane];
    uint4 bf3 = Bt[192 + lane];

    __syncthreads();

    // ---- Stage 2: MFMA. 72 positions (2 images x 36) = 5 tiles of 16 ----
    const unsigned* c1 = &cs1[0][0];
    for (int tile = wave; tile < 5; tile += 4) {
        const int p  = tile * 16 + n;
        const int pc = (p < 72) ? p : 71;          // clamp pad lanes (tile 4)
        const int im = (pc >= 36) ? 1 : 0;
        const int ps = pc - im * 36;
        const int i  = ps / 6;
        const int j  = ps - i * 6;
        // A row m=n -> position p; quad -> dy; 8 f16 = 16B of cs1 row.
        const unsigned base = (unsigned)(im * 784 + (2 * i + quad) * 14 + 2 * j);
        f4 acc = {0.f, 0.f, 0.f, 0.f};
        #pragma unroll
        for (int c = 0; c < 4; ++c) {
            uint2 lo = *(const uint2*)(c1 + base + c * 196);
            uint2 hi = *(const uint2*)(c1 + base + c * 196 + 2);
            uint4 a4 = make_uint4(lo.x, lo.y, hi.x, hi.y);
            v8h av = __builtin_bit_cast(v8h, a4);
            v8h bv = __builtin_bit_cast(v8h, (c == 0) ? bf0 : (c == 1) ? bf1
                                              : (c == 2) ? bf2 : bf3);
            acc = __builtin_amdgcn_mfma_f32_16x16x32_f16(av, bv, acc, 0, 0, 0);
        }
        // C/D: col = n, rows = quad*4 + r. X in even-n, Y in odd-n lanes.
        float pr0 = __shfl_xor(acc[0], 1);
        float pr1 = __shfl_xor(acc[1], 1);
        float pr2 = __shfl_xor(acc[2], 1);
        float pr3 = __shfl_xor(acc[3], 1);
        if (!(n & 1)) {
            const int o = n >> 1;
            float Xs[4] = {acc[0], acc[1], acc[2], acc[3]};
            float Ys[4] = {pr0, pr1, pr2, pr3};
            #pragma unroll
            for (int r = 0; r < 4; ++r) {
                const int p2 = tile * 16 + quad * 4 + r;
                if (p2 < 72) {
                    const int im2 = (p2 >= 36) ? 1 : 0;
                    const int ps2 = p2 - im2 * 36;
                    float X = Xs[r], Y = Ys[r];
                    float rinv = rsqrtf(fmaxf(fmaf(X, X, Y * Y), 1e-30f));
                    cs2[im2][ps2 * 8 + o] = packh2(X * rinv, Y * rinv);
                }
            }
        }
    }
    __syncthreads();

    // ---- Stage 3: ring-FF 288 -> 10 (2 waves/image, 5 outputs per wave) ----
    // wave half = wave&1: outputs n3 = half*5 + lane/12; g = lane%12 (60
    // active lanes); features f = g + 12k. 2-way split accumulators: the
    // serial fdot2 chain is 12 deep (was 24), loads of pair k+1 issue while
    // pair k's dots execute.
    {
        const int half = wave & 1;
        const int nl   = lane / 12;              // 0..4 active
        const int g    = lane - nl * 12;
        float X0 = 0.f, Y0 = 0.f, X1 = 0.f, Y1 = 0.f;
        if (nl < 5) {
            const int n3 = half * 5 + nl;
            #pragma unroll
            for (int k = 0; k < 24; k += 2) {
                const int f0 = g + 12 * k;
                const int f1 = f0 + 12;
                unsigned va = cs2[img][f0];
                unsigned vb = cs2[img][f1];
                uint2 wa = wt[WT_FF + f0 * 10 + n3];
                uint2 wb = wt[WT_FF + f1 * 10 + n3];
                X0 = fdot2(va, wa.x, X0); Y0 = fdot2(va, wa.y, Y0);
                X1 = fdot2(vb, wb.x, X1); Y1 = fdot2(vb, wb.y, Y1);
            }
        }
        float X = X0 + X1, Y = Y0 + Y1;
        // 12-lane group sum (valid at g==0): q = v+sh4+sh8; s = q+sh1+sh2+sh3
        float qX = X + __shfl_down(X, 4) + __shfl_down(X, 8);
        float qY = Y + __shfl_down(Y, 4) + __shfl_down(Y, 8);
        float sX = qX + __shfl_down(qX, 1) + __shfl_down(qX, 2) + __shfl_down(qX, 3);
        float sY = qY + __shfl_down(qY, 1) + __shfl_down(qY, 2) + __shfl_down(qY, 3);
        if (g == 0 && nl < 5) {
            const int n3 = half * 5 + nl;
            float rinv = rsqrtf(fmaxf(fmaf(sX, sX, sY * sY), 1e-30f));
            out[(b0 + img) * 10 + n3] = sY * rinv;
        }
    }
}

extern "C" void kernel_launch(void* const* d_in, const int* in_sizes, int n_in,
                              void* d_out, int out_size, void* d_ws, size_t ws_size,
                              hipStream_t stream) {
    const float* x   = (const float*)d_in[0];
    const float* w1  = (const float*)d_in[1];
    const float* w2  = (const float*)d_in[2];
    const float* ffw = (const float*)d_in[3];
    uint2* wt = (uint2*)d_ws;              // needs 27264 + 4096 = 31360 bytes
    float* o  = (float*)d_out;

    ringnn_setup<<<15, 256, 0, stream>>>(w1, w2, ffw, wt);
    ringnn_main<<<2048, 256, 0, stream>>>(x, wt, o);
}